// Round 3
// baseline (173.778 us; speedup 1.0000x reference)
//
#include <hip/hip_runtime.h>
#include <hip/hip_bf16.h>

// Problem constants
#define BATCH 2
#define SEQ   2048
#define DMODEL 1024
#define NHEADS 16
#define DHEAD  64
#define MTOT   (BATCH * SEQ)         // 4096 rows
#define QKSTR  2048                  // q,k buffer row stride (v stored separately)

typedef __attribute__((ext_vector_type(8))) short bf16x8;   // 8 bf16 in 4 VGPRs
typedef __attribute__((ext_vector_type(4))) float f32x4;

// 16B async global->LDS copy (LDS dest = wave-uniform base + lane*16).
__device__ __forceinline__ void glds16(const void* g, void* l)
{
    __builtin_amdgcn_global_load_lds(
        (const __attribute__((address_space(1))) unsigned int*)g,
        (__attribute__((address_space(3))) unsigned int*)l, 16, 0, 0);
}

// v_cvt_pk_bf16_f32: dst.lo = bf16(lo), dst.hi = bf16(hi). No builtin (m240).
__device__ __forceinline__ unsigned cvt_pk_bf16(float lo, float hi)
{
    unsigned r;
    asm("v_cvt_pk_bf16_f32 %0, %1, %2" : "=v"(r) : "v"(lo), "v"(hi));
    return r;
}

// ---------------------------------------------------------------------------
// fused fp32 -> bf16 casts (x, qkv_w, proj_w in one launch)
// ---------------------------------------------------------------------------
__global__ void cast_all_kernel(
    const float* __restrict__ a, __hip_bfloat16* __restrict__ oa, int na4,
    const float* __restrict__ b, __hip_bfloat16* __restrict__ ob, int nb4,
    const float* __restrict__ c, __hip_bfloat16* __restrict__ oc, int nc4)
{
    int i = blockIdx.x * blockDim.x + threadIdx.x;
    const float* src; __hip_bfloat16* dst; int j = i;
    if (j < na4) { src = a; dst = oa; }
    else {
        j -= na4;
        if (j < nb4) { src = b; dst = ob; }
        else {
            j -= nb4;
            if (j >= nc4) return;
            src = c; dst = oc;
        }
    }
    float4 v = ((const float4*)src)[j];
    __hip_bfloat16 tmp[4];
    tmp[0] = __float2bfloat16(v.x);
    tmp[1] = __float2bfloat16(v.y);
    tmp[2] = __float2bfloat16(v.z);
    tmp[3] = __float2bfloat16(v.w);
    *(uint2*)(dst + 4 * (size_t)j) = *(const uint2*)tmp;
}

// ---------------------------------------------------------------------------
// GEMM: out[M,N] = A[M,K] @ W[N,K]^T + bias[N]; bf16 in, fp32 acc.
// 64xTN tile, BK=64, global_load_lds(16B) staging, XOR-swizzled LDS.
// MODE 0: plain store (stride N). MODE 1 (qkv, TN=128): cols<2048 RoPE pairs
// into qk buffer (stride QKSTR); cols>=2048 V transposed to vtg[(b,h),dh,s].
// ---------------------------------------------------------------------------
#define GTM 64
#define GBK 64

__device__ __forceinline__ void store_out(float* p, float v) { *p = v; }
__device__ __forceinline__ void store_out(__hip_bfloat16* p, float v) { *p = __float2bfloat16(v); }

template <typename OutT, int MODE, int TN>
__global__ __launch_bounds__(256, 6) void gemm_bias_kernel(
    const __hip_bfloat16* __restrict__ A, const __hip_bfloat16* __restrict__ W,
    const float* __restrict__ bias, OutT* __restrict__ out,
    __hip_bfloat16* __restrict__ vtg,
    int M, int N, int K)
{
    const int NI = TN / 32;                    // n-frags per wave
    const int bm = blockIdx.x * GTM;
    const int bn = blockIdx.y * TN;
    const int tid = threadIdx.x;
    const int wave = tid >> 6;
    const int lane = tid & 63;
    const int quad = lane >> 4;
    const int l16 = lane & 15;
    const int wm = (wave & 1) * 32;
    const int wn = (wave >> 1) * (TN / 2);

    __shared__ __hip_bfloat16 As[GTM * GBK];   // 8 KB
    __shared__ __hip_bfloat16 Bs[TN * GBK];    // 16 KB (TN=128) / 8 KB (TN=64)

    f32x4 acc[2][NI] = {};

    const int srow = lane >> 3;
    const int gc8 = (((lane & 7) ^ srow)) * 8;

    for (int kt = 0; kt < K; kt += GBK) {
#pragma unroll
        for (int t = 0; t < 2; t++) {          // A: 8 chunks of 8 rows, 2/wave
            int i = wave * 2 + t;
            glds16(A + (size_t)(bm + i * 8 + srow) * K + kt + gc8, As + i * 512);
        }
#pragma unroll
        for (int t = 0; t < TN / 32; t++) {    // B: TN/8 chunks, (TN/32)/wave
            int i = wave * (TN / 32) + t;
            glds16(W + (size_t)(bn + i * 8 + srow) * K + kt + gc8, Bs + i * 512);
        }
        __syncthreads();

#pragma unroll
        for (int kk = 0; kk < 2; kk++) {
            bf16x8 af[2], bfr[NI];
#pragma unroll
            for (int i = 0; i < 2; i++) {
                int ra = wm + i * 16 + l16;
                af[i] = *(const bf16x8*)(As + ra * 64 + (((kk << 2) + quad) ^ (ra & 7)) * 8);
            }
#pragma unroll
            for (int i = 0; i < NI; i++) {
                int rb = wn + i * 16 + l16;
                bfr[i] = *(const bf16x8*)(Bs + rb * 64 + (((kk << 2) + quad) ^ (rb & 7)) * 8);
            }
#pragma unroll
            for (int mi = 0; mi < 2; mi++)
#pragma unroll
                for (int ni = 0; ni < NI; ni++)
                    acc[mi][ni] = __builtin_amdgcn_mfma_f32_16x16x32_bf16(
                        af[mi], bfr[ni], acc[mi][ni], 0, 0, 0);
        }
        __syncthreads();
    }

    if (MODE == 1 && (bn + wn) < 2 * DMODEL) {
        // q/k columns: RoPE pairs (dh, dh+32) = (acc[.][ni], acc[.][ni+2])
#pragma unroll
        for (int ni = 0; ni < 2; ni++) {
            int col = bn + wn + ni * 16 + l16;
            int i32 = col & 31;
            float invf = exp2f(-13.287712379549449f * (float)i32 * (1.0f / 32.0f));
            float b1 = bias[col], b2 = bias[col + 32];
#pragma unroll
            for (int mi = 0; mi < 2; mi++) {
#pragma unroll
                for (int r = 0; r < 4; r++) {
                    int row = bm + wm + mi * 16 + quad * 4 + r;
                    int s = row & (SEQ - 1);
                    float ang = (float)s * invf;
                    float sn, cs;
                    __sincosf(ang, &sn, &cs);
                    float x1 = acc[mi][ni][r] + b1;
                    float x2 = acc[mi][ni + 2][r] + b2;
                    store_out(&out[(size_t)row * QKSTR + col], x1 * cs - x2 * sn);
                    store_out(&out[(size_t)row * QKSTR + col + 32], x2 * cs + x1 * sn);
                }
            }
        }
    } else if (MODE == 1) {
        // V columns: write transposed into vtg[(b*16+h)*64 + dh][s], 8B packed
#pragma unroll
        for (int ni = 0; ni < NI; ni++) {
            int colg = bn + wn + ni * 16 + l16;
            int vcol = colg - 2 * DMODEL;
            int hh = vcol >> 6, dh = vcol & 63;
            float bv = bias[colg];
#pragma unroll
            for (int mi = 0; mi < 2; mi++) {
                int row0 = bm + wm + mi * 16 + quad * 4;
                int bb = row0 >> 11;
                int ss = row0 & (SEQ - 1);
                __hip_bfloat16 tmp[4];
#pragma unroll
                for (int r = 0; r < 4; r++)
                    tmp[r] = __float2bfloat16(acc[mi][ni][r] + bv);
                *(uint2*)(vtg + (((size_t)bb * NHEADS + hh) * DHEAD + dh) * SEQ + ss) =
                    *(uint2*)tmp;
            }
        }
    } else {
#pragma unroll
        for (int mi = 0; mi < 2; mi++)
#pragma unroll
            for (int ni = 0; ni < NI; ni++) {
                int col = bn + wn + ni * 16 + l16;
                float bv = bias[col];
#pragma unroll
                for (int r = 0; r < 4; r++) {
                    int row = bm + wm + mi * 16 + quad * 4 + r;
                    store_out(&out[(size_t)row * N + col], acc[mi][ni][r] + bv);
                }
            }
    }
}

// ---------------------------------------------------------------------------
// MFMA flash attention v6: 4-wave blocks, swapped-QK packed softmax.
// v5 post-mortem: uniform schedule didn't help -> limiter is the per-iteration
// serial chain (barrier/vmcnt drain + softmax VALU + P LDS roundtrip) with
// only 2 barrier domains/CU to overlap stalls.
// v6: (a) one q-tile per 4-wave block; grid 32bh x 32qt = 1024 blocks, 40KB
// LDS -> 4 blocks/CU (4 independent barrier domains; same 16 waves/CU).
// Longest blocks dispatched first (qt = 31-y); x-major order deals each CU
// one block per length quartile (~64 iter-units each, balanced).
// (b) swapped QK^T: mfma(K,Q) -> lane holds S[q=l16][k=nt*16+quad*4+r];
// consecutive r = consecutive k, so P packs via v_cvt_pk_bf16_f32 pairs and
// stores with 4 ds_write_b64 at LOOP-INVARIANT addresses (replaces 16 scalar
// cvt + 16 ds_write_b16 + per-tile swizzle math). LDS P layout & PV reads
// byte-identical to the proven conflict-free pattern. Operand register
// contents for the swapped mfma are identical to the originals (verified by
// layout derivation); O/ones/epilogue layouts unchanged.
// (c) s_setprio(1) around MFMA clusters (T5, attn +4-7%).
// Per wave per k-tile: 8 QK + 10 PV MFMAs (row-sum l via ones B-frag).
// ---------------------------------------------------------------------------
__global__ __launch_bounds__(256, 4) void flash_attn_mfma_kernel(
    const __hip_bfloat16* __restrict__ qkb,
    const __hip_bfloat16* __restrict__ vtg,
    __hip_bfloat16* __restrict__ ctx)
{
    const int bh = blockIdx.x;
    const int b = bh >> 4, h = bh & 15;
    const int qt = 31 - blockIdx.y;         // longest first
    const int tid = threadIdx.x;
    const int w = tid >> 6;                 // 0..3: 16-row q band
    const int lane = tid & 63;
    const int quad = lane >> 4;
    const int l16 = lane & 15;

    __shared__ alignas(16) __hip_bfloat16 Ks[2][64 * 64];  // 16 KB [key][dh] swz
    __shared__ alignas(16) __hip_bfloat16 Vt[2][64 * 64];  // 16 KB [dh][key] swz
    __shared__ alignas(16) __hip_bfloat16 Ps[64 * 64];     //  8 KB [q][k] swz, wave bands

    const __hip_bfloat16* qbase = qkb + (size_t)b * SEQ * QKSTR + h * DHEAD;
    const __hip_bfloat16* kbase = qbase + DMODEL;
    const __hip_bfloat16* vbase = vtg + (size_t)bh * DHEAD * SEQ;

    // Q fragment (B-operand of swapped QK): content = Q[q=l16 band row][dh=quad*8+j]
    const __hip_bfloat16* qrow = qbase + (size_t)(qt * 64 + w * 16 + l16) * QKSTR;
    bf16x8 qf0 = *(const bf16x8*)(qrow + quad * 8);
    bf16x8 qf1 = *(const bf16x8*)(qrow + 32 + quad * 8);

    // staging: wave w stages rows [w*16, w*16+16) of K tile and of Vt tile
    const int srow = lane >> 3;
    const int gc8 = ((lane & 7) ^ srow) * 8;          // XOR swizzle, matches readers
    const __hip_bfloat16* kg = kbase + (size_t)(w * 16 + srow) * QKSTR + gc8;
    const __hip_bfloat16* vg = vbase + (size_t)(w * 16 + srow) * SEQ + gc8;

    // hoisted LDS offsets (all loop-invariant)
    const int xr = l16 & 7;
    const int fo0 = l16 * 64 + ((quad ^ xr) << 3);          // K/V kk=0 chunk
    const int fo1 = l16 * 64 + (((4 + quad) ^ xr) << 3);    // kk=1
    const int pband = w * 16;
    char* const psb = (char*)Ps;
    // P A-frag reads (bytes): row pband+l16, chunk (4kk+quad)^xr
    const int pr0 = (pband + l16) * 128 + ((quad ^ xr) << 4);
    const int pr1 = (pband + l16) * 128 + (((4 + quad) ^ xr) << 4);
    // P b64 store offsets (bytes): chunk (2nt+(quad>>1))^xr, halfsel (quad&1)*8
    int pwc[4];
#pragma unroll
    for (int nt = 0; nt < 4; nt++)
        pwc[nt] = (pband + l16) * 128 +
                  ((((nt << 1) + (quad >> 1)) ^ xr) << 4) + (quad & 1) * 8;

    const short onev = (l16 == 0) ? (short)0x3F80 : (short)0;
    const bf16x8 ones = {onev, onev, onev, onev, onev, onev, onev, onev};

    f32x4 oacc[5] = {};

    auto stage = [&](int t, int buf) {
        const __hip_bfloat16* kt_ = kg + (size_t)t * 64 * QKSTR;
        const __hip_bfloat16* vt_ = vg + t * 64;
        glds16(kt_,              &Ks[buf][w * 1024]);
        glds16(kt_ + 8 * QKSTR,  &Ks[buf][w * 1024 + 512]);
        glds16(vt_,              &Vt[buf][w * 1024]);
        glds16(vt_ + 8 * SEQ,    &Vt[buf][w * 1024 + 512]);
    };

    stage(0, 0);

    for (int jt = 0; jt <= qt; jt++) {
        __syncthreads();                      // staged tile ready (vmcnt drain)
        const int cur = jt & 1;
        if (jt < qt) stage(jt + 1, cur ^ 1);
        const __hip_bfloat16* ks = Ks[cur];
        const __hip_bfloat16* vs = Vt[cur];

        // S^T = K Q^T : 8 MFMAs; lane holds S[q=l16][k=nt*16+quad*4+r]
        f32x4 s4[4] = {};
        __builtin_amdgcn_s_setprio(1);
#pragma unroll
        for (int nt = 0; nt < 4; nt++)
            s4[nt] = __builtin_amdgcn_mfma_f32_16x16x32_bf16(
                *(const bf16x8*)(ks + nt * 1024 + fo0), qf0, s4[nt], 0, 0, 0);
#pragma unroll
        for (int nt = 0; nt < 4; nt++)
            s4[nt] = __builtin_amdgcn_mfma_f32_16x16x32_bf16(
                *(const bf16x8*)(ks + nt * 1024 + fo1), qf1, s4[nt], 0, 0, 0);
        __builtin_amdgcn_s_setprio(0);

        // p = exp(s/8) = exp2(s*0.18033688); pack pairs (adjacent k), 4x b64 store
        const bool diag = (jt == qt);
        const int qq = w * 16 + l16;          // q within tile
#pragma unroll
        for (int nt = 0; nt < 4; nt++) {
            float p0 = exp2f(s4[nt][0] * 0.1803368801f);
            float p1 = exp2f(s4[nt][1] * 0.1803368801f);
            float p2 = exp2f(s4[nt][2] * 0.1803368801f);
            float p3 = exp2f(s4[nt][3] * 0.1803368801f);
            if (diag) {
                int k0 = nt * 16 + quad * 4;
                p0 = (k0 + 0 <= qq) ? p0 : 0.f;
                p1 = (k0 + 1 <= qq) ? p1 : 0.f;
                p2 = (k0 + 2 <= qq) ? p2 : 0.f;
                p3 = (k0 + 3 <= qq) ? p3 : 0.f;
            }
            uint2 pv;
            pv.x = cvt_pk_bf16(p0, p1);
            pv.y = cvt_pk_bf16(p2, p3);
            *(uint2*)(psb + pwc[nt]) = pv;    // ds_write_b64, hoisted addr
        }

        // O += P V (ones-frag 5th tile accumulates l): 10 MFMAs
        bf16x8 pf0 = *(const bf16x8*)(psb + pr0);
        bf16x8 pf1 = *(const bf16x8*)(psb + pr1);
        __builtin_amdgcn_s_setprio(1);
#pragma unroll
        for (int dt = 0; dt < 4; dt++)
            oacc[dt] = __builtin_amdgcn_mfma_f32_16x16x32_bf16(
                pf0, *(const bf16x8*)(vs + dt * 1024 + fo0), oacc[dt], 0, 0, 0);
        oacc[4] = __builtin_amdgcn_mfma_f32_16x16x32_bf16(pf0, ones, oacc[4], 0, 0, 0);
#pragma unroll
        for (int dt = 0; dt < 4; dt++)
            oacc[dt] = __builtin_amdgcn_mfma_f32_16x16x32_bf16(
                pf1, *(const bf16x8*)(vs + dt * 1024 + fo1), oacc[dt], 0, 0, 0);
        oacc[4] = __builtin_amdgcn_mfma_f32_16x16x32_bf16(pf1, ones, oacc[4], 0, 0, 0);
        __builtin_amdgcn_s_setprio(0);
    }

    // epilogue: l sits in oacc[4][r] at lanes l16==0 of each quad
#pragma unroll
    for (int r = 0; r < 4; r++) {
        float lv = __shfl(oacc[4][r], lane & 48);
        float il = 1.0f / lv;
        int qg = qt * 64 + w * 16 + quad * 4 + r;
        __hip_bfloat16* op = ctx + (((size_t)b * SEQ + qg) * NHEADS + h) * DHEAD + l16;
#pragma unroll
        for (int dt = 0; dt < 4; dt++)
            op[dt * 16] = __float2bfloat16(oacc[dt][r] * il);
    }
}

// ---------------------------------------------------------------------------
extern "C" void kernel_launch(void* const* d_in, const int* in_sizes, int n_in,
                              void* d_out, int out_size, void* d_ws, size_t ws_size,
                              hipStream_t stream)
{
    const float* x      = (const float*)d_in[0];   // [2,2048,1024]
    const float* qkv_w  = (const float*)d_in[1];   // [3072,1024]
    const float* qkv_b  = (const float*)d_in[2];   // [3072]
    const float* proj_w = (const float*)d_in[3];   // [1024,1024]
    const float* proj_b = (const float*)d_in[4];   // [1024]
    float* out = (float*)d_out;                    // [2,2048,1024]

    char* w = (char*)d_ws;
    __hip_bfloat16* qkb = (__hip_bfloat16*)w;  w += (size_t)MTOT * QKSTR * 2;         // 16 MB
    __hip_bfloat16* vtg = (__hip_bfloat16*)w;  w += (size_t)MTOT * DMODEL * 2;        //  8 MB
    __hip_bfloat16* ctx = (__hip_bfloat16*)w;  w += (size_t)MTOT * DMODEL * 2;        //  8 MB
    __hip_bfloat16* xb  = (__hip_bfloat16*)w;  w += (size_t)MTOT * DMODEL * 2;        //  8 MB
    __hip_bfloat16* wqk = (__hip_bfloat16*)w;  w += (size_t)3 * DMODEL * DMODEL * 2;  //  6 MB
    __hip_bfloat16* wpr = (__hip_bfloat16*)w;                                         //  2 MB

    const int na4 = MTOT * DMODEL / 4;
    const int nb4 = 3 * DMODEL * DMODEL / 4;
    const int nc4 = DMODEL * DMODEL / 4;

    // 0) fused bf16 casts
    cast_all_kernel<<<(na4 + nb4 + nc4 + 255) / 256, 256, 0, stream>>>(
        x, xb, na4, qkv_w, wqk, nb4, proj_w, wpr, nc4);

    // 1) qkv projection: q,k (RoPE'd) -> qkb; V -> vtg (transposed), fused
    //    64x128 tiles -> 1536 blocks = 6/CU
    gemm_bias_kernel<__hip_bfloat16, 1, 128>
        <<<dim3(MTOT / GTM, (3 * DMODEL) / 128), 256, 0, stream>>>(
        xb, wqk, qkv_b, qkb, vtg, MTOT, 3 * DMODEL, DMODEL);

    // 2) causal MFMA flash attention -> ctx [B,S,H,Dh] bf16
    //    1024 blocks of 256 thr, 40KB LDS -> 4 blocks/CU
    flash_attn_mfma_kernel<<<dim3(BATCH * NHEADS, 32), 256, 0, stream>>>(qkb, vtg, ctx);

    // 3) out = ctx @ proj_w^T + proj_b -> fp32 d_out
    //    64x64 tiles -> 1024 blocks = 4/CU
    gemm_bias_kernel<float, 0, 64>
        <<<dim3(MTOT / GTM, DMODEL / 64), 256, 0, stream>>>(
        ctx, wpr, proj_b, out, nullptr, MTOT, DMODEL, DMODEL);
}

// Round 4
// 168.565 us; speedup vs baseline: 1.0309x; 1.0309x over previous
//
#include <hip/hip_runtime.h>
#include <hip/hip_bf16.h>

// Problem constants
#define BATCH 2
#define SEQ   2048
#define DMODEL 1024
#define NHEADS 16
#define DHEAD  64
#define MTOT   (BATCH * SEQ)         // 4096 rows
#define QKSTR  2048                  // q,k buffer row stride (v stored separately)

typedef __attribute__((ext_vector_type(8))) short bf16x8;   // 8 bf16 in 4 VGPRs
typedef __attribute__((ext_vector_type(4))) float f32x4;

// 16B async global->LDS copy (LDS dest = wave-uniform base + lane*16).
__device__ __forceinline__ void glds16(const void* g, void* l)
{
    __builtin_amdgcn_global_load_lds(
        (const __attribute__((address_space(1))) unsigned int*)g,
        (__attribute__((address_space(3))) unsigned int*)l, 16, 0, 0);
}

// v_cvt_pk_bf16_f32: dst.lo = bf16(lo), dst.hi = bf16(hi). No builtin (m240).
__device__ __forceinline__ unsigned cvt_pk_bf16(float lo, float hi)
{
    unsigned r;
    asm("v_cvt_pk_bf16_f32 %0, %1, %2" : "=v"(r) : "v"(lo), "v"(hi));
    return r;
}

// ---------------------------------------------------------------------------
// fused fp32 -> bf16 casts (x, qkv_w, proj_w in one launch)
// ---------------------------------------------------------------------------
__global__ void cast_all_kernel(
    const float* __restrict__ a, __hip_bfloat16* __restrict__ oa, int na4,
    const float* __restrict__ b, __hip_bfloat16* __restrict__ ob, int nb4,
    const float* __restrict__ c, __hip_bfloat16* __restrict__ oc, int nc4)
{
    int i = blockIdx.x * blockDim.x + threadIdx.x;
    const float* src; __hip_bfloat16* dst; int j = i;
    if (j < na4) { src = a; dst = oa; }
    else {
        j -= na4;
        if (j < nb4) { src = b; dst = ob; }
        else {
            j -= nb4;
            if (j >= nc4) return;
            src = c; dst = oc;
        }
    }
    float4 v = ((const float4*)src)[j];
    __hip_bfloat16 tmp[4];
    tmp[0] = __float2bfloat16(v.x);
    tmp[1] = __float2bfloat16(v.y);
    tmp[2] = __float2bfloat16(v.z);
    tmp[3] = __float2bfloat16(v.w);
    *(uint2*)(dst + 4 * (size_t)j) = *(const uint2*)tmp;
}

// ---------------------------------------------------------------------------
// GEMM: out[M,N] = A[M,K] @ W[N,K]^T + bias[N]; bf16 in, fp32 acc.
// TMxTN tile (template), BK=64, global_load_lds(16B) staging, XOR-swizzled
// LDS (chunk ^ (row&7), 64-el rows -> conflict-free; r6-verified). 4 waves in
// a 2x2 grid: wm=(wave&1)*(TM/2), wn=(wave>>1)*(TN/2); per-wave acc is
// (TM/32)x(TN/32) 16x16 frags. v7: qkv moved to 128x128 (32 MFMA/K-step,
// grid 768 = 3/CU, the m97-ladder sweet spot); proj to 64x128 (512 = 2/CU).
// MODE 0: plain store (stride N). MODE 1 (qkv): cols<2048 RoPE pairs into qk
// buffer (stride QKSTR); cols>=2048 V transposed to vtg[(b,h),dh,s].
// ---------------------------------------------------------------------------
#define GBK 64

__device__ __forceinline__ void store_out(float* p, float v) { *p = v; }
__device__ __forceinline__ void store_out(__hip_bfloat16* p, float v) { *p = __float2bfloat16(v); }

template <typename OutT, int MODE, int TM, int TN, int MINW>
__global__ __launch_bounds__(256, MINW) void gemm_bias_kernel(
    const __hip_bfloat16* __restrict__ A, const __hip_bfloat16* __restrict__ W,
    const float* __restrict__ bias, OutT* __restrict__ out,
    __hip_bfloat16* __restrict__ vtg,
    int M, int N, int K)
{
    const int MI = TM / 32;                    // m-frags per wave
    const int NI = TN / 32;                    // n-frags per wave
    const int bm = blockIdx.x * TM;
    const int bn = blockIdx.y * TN;
    const int tid = threadIdx.x;
    const int wave = tid >> 6;
    const int lane = tid & 63;
    const int quad = lane >> 4;
    const int l16 = lane & 15;
    const int wm = (wave & 1) * (TM / 2);
    const int wn = (wave >> 1) * (TN / 2);

    __shared__ __hip_bfloat16 As[TM * GBK];    // TM/64 * 8 KB
    __shared__ __hip_bfloat16 Bs[TN * GBK];    // TN/64 * 8 KB

    f32x4 acc[MI][NI] = {};

    const int srow = lane >> 3;
    const int gc8 = (((lane & 7) ^ srow)) * 8;

    for (int kt = 0; kt < K; kt += GBK) {
#pragma unroll
        for (int t = 0; t < MI; t++) {         // A: TM/8 chunks of 8 rows, MI/wave
            int i = wave * MI + t;
            glds16(A + (size_t)(bm + i * 8 + srow) * K + kt + gc8, As + i * 512);
        }
#pragma unroll
        for (int t = 0; t < NI; t++) {         // B: TN/8 chunks, NI/wave
            int i = wave * NI + t;
            glds16(W + (size_t)(bn + i * 8 + srow) * K + kt + gc8, Bs + i * 512);
        }
        __syncthreads();

#pragma unroll
        for (int kk = 0; kk < 2; kk++) {
            bf16x8 af[MI], bfr[NI];
#pragma unroll
            for (int i = 0; i < MI; i++) {
                int ra = wm + i * 16 + l16;
                af[i] = *(const bf16x8*)(As + ra * 64 + (((kk << 2) + quad) ^ (ra & 7)) * 8);
            }
#pragma unroll
            for (int i = 0; i < NI; i++) {
                int rb = wn + i * 16 + l16;
                bfr[i] = *(const bf16x8*)(Bs + rb * 64 + (((kk << 2) + quad) ^ (rb & 7)) * 8);
            }
#pragma unroll
            for (int mi = 0; mi < MI; mi++)
#pragma unroll
                for (int ni = 0; ni < NI; ni++)
                    acc[mi][ni] = __builtin_amdgcn_mfma_f32_16x16x32_bf16(
                        af[mi], bfr[ni], acc[mi][ni], 0, 0, 0);
        }
        __syncthreads();
    }

    if (MODE == 1 && (bn + wn) < 2 * DMODEL) {
        // q/k columns: RoPE pairs (dh, dh+32) = (acc[.][ni], acc[.][ni+2]).
        // Wave spans TN/2 = 64 cols; ni<2 paired with ni+2 covers all of them.
#pragma unroll
        for (int ni = 0; ni < 2; ni++) {
            int col = bn + wn + ni * 16 + l16;
            int i32 = col & 31;
            float invf = exp2f(-13.287712379549449f * (float)i32 * (1.0f / 32.0f));
            float b1 = bias[col], b2 = bias[col + 32];
#pragma unroll
            for (int mi = 0; mi < MI; mi++) {
#pragma unroll
                for (int r = 0; r < 4; r++) {
                    int row = bm + wm + mi * 16 + quad * 4 + r;
                    int s = row & (SEQ - 1);
                    float ang = (float)s * invf;
                    float sn, cs;
                    __sincosf(ang, &sn, &cs);
                    float x1 = acc[mi][ni][r] + b1;
                    float x2 = acc[mi][ni + 2][r] + b2;
                    store_out(&out[(size_t)row * QKSTR + col], x1 * cs - x2 * sn);
                    store_out(&out[(size_t)row * QKSTR + col + 32], x2 * cs + x1 * sn);
                }
            }
        }
    } else if (MODE == 1) {
        // V columns: write transposed into vtg[(b*16+h)*64 + dh][s], 8B packed
#pragma unroll
        for (int ni = 0; ni < NI; ni++) {
            int colg = bn + wn + ni * 16 + l16;
            int vcol = colg - 2 * DMODEL;
            int hh = vcol >> 6, dh = vcol & 63;
            float bv = bias[colg];
#pragma unroll
            for (int mi = 0; mi < MI; mi++) {
                int row0 = bm + wm + mi * 16 + quad * 4;
                int bb = row0 >> 11;
                int ss = row0 & (SEQ - 1);
                __hip_bfloat16 tmp[4];
#pragma unroll
                for (int r = 0; r < 4; r++)
                    tmp[r] = __float2bfloat16(acc[mi][ni][r] + bv);
                *(uint2*)(vtg + (((size_t)bb * NHEADS + hh) * DHEAD + dh) * SEQ + ss) =
                    *(uint2*)tmp;
            }
        }
    } else {
#pragma unroll
        for (int mi = 0; mi < MI; mi++)
#pragma unroll
            for (int ni = 0; ni < NI; ni++) {
                int col = bn + wn + ni * 16 + l16;
                float bv = bias[col];
#pragma unroll
                for (int r = 0; r < 4; r++) {
                    int row = bm + wm + mi * 16 + quad * 4 + r;
                    store_out(&out[(size_t)row * N + col], acc[mi][ni][r] + bv);
                }
            }
    }
}

// ---------------------------------------------------------------------------
// MFMA flash attention v6 (unchanged): 4-wave blocks, swapped-QK packed
// softmax, 4 blocks/CU, longest-first dispatch, s_setprio around MFMA
// clusters. Per wave per k-tile: 8 QK + 10 PV MFMAs (row-sum l via ones
// B-frag). All dispatches now <44 us (dropped out of rocprof top-5).
// ---------------------------------------------------------------------------
__global__ __launch_bounds__(256, 4) void flash_attn_mfma_kernel(
    const __hip_bfloat16* __restrict__ qkb,
    const __hip_bfloat16* __restrict__ vtg,
    __hip_bfloat16* __restrict__ ctx)
{
    const int bh = blockIdx.x;
    const int b = bh >> 4, h = bh & 15;
    const int qt = 31 - blockIdx.y;         // longest first
    const int tid = threadIdx.x;
    const int w = tid >> 6;                 // 0..3: 16-row q band
    const int lane = tid & 63;
    const int quad = lane >> 4;
    const int l16 = lane & 15;

    __shared__ alignas(16) __hip_bfloat16 Ks[2][64 * 64];  // 16 KB [key][dh] swz
    __shared__ alignas(16) __hip_bfloat16 Vt[2][64 * 64];  // 16 KB [dh][key] swz
    __shared__ alignas(16) __hip_bfloat16 Ps[64 * 64];     //  8 KB [q][k] swz, wave bands

    const __hip_bfloat16* qbase = qkb + (size_t)b * SEQ * QKSTR + h * DHEAD;
    const __hip_bfloat16* kbase = qbase + DMODEL;
    const __hip_bfloat16* vbase = vtg + (size_t)bh * DHEAD * SEQ;

    // Q fragment (B-operand of swapped QK): content = Q[q=l16 band row][dh=quad*8+j]
    const __hip_bfloat16* qrow = qbase + (size_t)(qt * 64 + w * 16 + l16) * QKSTR;
    bf16x8 qf0 = *(const bf16x8*)(qrow + quad * 8);
    bf16x8 qf1 = *(const bf16x8*)(qrow + 32 + quad * 8);

    // staging: wave w stages rows [w*16, w*16+16) of K tile and of Vt tile
    const int srow = lane >> 3;
    const int gc8 = ((lane & 7) ^ srow) * 8;          // XOR swizzle, matches readers
    const __hip_bfloat16* kg = kbase + (size_t)(w * 16 + srow) * QKSTR + gc8;
    const __hip_bfloat16* vg = vbase + (size_t)(w * 16 + srow) * SEQ + gc8;

    // hoisted LDS offsets (all loop-invariant)
    const int xr = l16 & 7;
    const int fo0 = l16 * 64 + ((quad ^ xr) << 3);          // K/V kk=0 chunk
    const int fo1 = l16 * 64 + (((4 + quad) ^ xr) << 3);    // kk=1
    const int pband = w * 16;
    char* const psb = (char*)Ps;
    // P A-frag reads (bytes): row pband+l16, chunk (4kk+quad)^xr
    const int pr0 = (pband + l16) * 128 + ((quad ^ xr) << 4);
    const int pr1 = (pband + l16) * 128 + (((4 + quad) ^ xr) << 4);
    // P b64 store offsets (bytes): chunk (2nt+(quad>>1))^xr, halfsel (quad&1)*8
    int pwc[4];
#pragma unroll
    for (int nt = 0; nt < 4; nt++)
        pwc[nt] = (pband + l16) * 128 +
                  ((((nt << 1) + (quad >> 1)) ^ xr) << 4) + (quad & 1) * 8;

    const short onev = (l16 == 0) ? (short)0x3F80 : (short)0;
    const bf16x8 ones = {onev, onev, onev, onev, onev, onev, onev, onev};

    f32x4 oacc[5] = {};

    auto stage = [&](int t, int buf) {
        const __hip_bfloat16* kt_ = kg + (size_t)t * 64 * QKSTR;
        const __hip_bfloat16* vt_ = vg + t * 64;
        glds16(kt_,              &Ks[buf][w * 1024]);
        glds16(kt_ + 8 * QKSTR,  &Ks[buf][w * 1024 + 512]);
        glds16(vt_,              &Vt[buf][w * 1024]);
        glds16(vt_ + 8 * SEQ,    &Vt[buf][w * 1024 + 512]);
    };

    stage(0, 0);

    for (int jt = 0; jt <= qt; jt++) {
        __syncthreads();                      // staged tile ready (vmcnt drain)
        const int cur = jt & 1;
        if (jt < qt) stage(jt + 1, cur ^ 1);
        const __hip_bfloat16* ks = Ks[cur];
        const __hip_bfloat16* vs = Vt[cur];

        // S^T = K Q^T : 8 MFMAs; lane holds S[q=l16][k=nt*16+quad*4+r]
        f32x4 s4[4] = {};
        __builtin_amdgcn_s_setprio(1);
#pragma unroll
        for (int nt = 0; nt < 4; nt++)
            s4[nt] = __builtin_amdgcn_mfma_f32_16x16x32_bf16(
                *(const bf16x8*)(ks + nt * 1024 + fo0), qf0, s4[nt], 0, 0, 0);
#pragma unroll
        for (int nt = 0; nt < 4; nt++)
            s4[nt] = __builtin_amdgcn_mfma_f32_16x16x32_bf16(
                *(const bf16x8*)(ks + nt * 1024 + fo1), qf1, s4[nt], 0, 0, 0);
        __builtin_amdgcn_s_setprio(0);

        // p = exp(s/8) = exp2(s*0.18033688); pack pairs (adjacent k), 4x b64 store
        const bool diag = (jt == qt);
        const int qq = w * 16 + l16;          // q within tile
#pragma unroll
        for (int nt = 0; nt < 4; nt++) {
            float p0 = exp2f(s4[nt][0] * 0.1803368801f);
            float p1 = exp2f(s4[nt][1] * 0.1803368801f);
            float p2 = exp2f(s4[nt][2] * 0.1803368801f);
            float p3 = exp2f(s4[nt][3] * 0.1803368801f);
            if (diag) {
                int k0 = nt * 16 + quad * 4;
                p0 = (k0 + 0 <= qq) ? p0 : 0.f;
                p1 = (k0 + 1 <= qq) ? p1 : 0.f;
                p2 = (k0 + 2 <= qq) ? p2 : 0.f;
                p3 = (k0 + 3 <= qq) ? p3 : 0.f;
            }
            uint2 pv;
            pv.x = cvt_pk_bf16(p0, p1);
            pv.y = cvt_pk_bf16(p2, p3);
            *(uint2*)(psb + pwc[nt]) = pv;    // ds_write_b64, hoisted addr
        }

        // O += P V (ones-frag 5th tile accumulates l): 10 MFMAs
        bf16x8 pf0 = *(const bf16x8*)(psb + pr0);
        bf16x8 pf1 = *(const bf16x8*)(psb + pr1);
        __builtin_amdgcn_s_setprio(1);
#pragma unroll
        for (int dt = 0; dt < 4; dt++)
            oacc[dt] = __builtin_amdgcn_mfma_f32_16x16x32_bf16(
                pf0, *(const bf16x8*)(vs + dt * 1024 + fo0), oacc[dt], 0, 0, 0);
        oacc[4] = __builtin_amdgcn_mfma_f32_16x16x32_bf16(pf0, ones, oacc[4], 0, 0, 0);
#pragma unroll
        for (int dt = 0; dt < 4; dt++)
            oacc[dt] = __builtin_amdgcn_mfma_f32_16x16x32_bf16(
                pf1, *(const bf16x8*)(vs + dt * 1024 + fo1), oacc[dt], 0, 0, 0);
        oacc[4] = __builtin_amdgcn_mfma_f32_16x16x32_bf16(pf1, ones, oacc[4], 0, 0, 0);
        __builtin_amdgcn_s_setprio(0);
    }

    // epilogue: l sits in oacc[4][r] at lanes l16==0 of each quad
#pragma unroll
    for (int r = 0; r < 4; r++) {
        float lv = __shfl(oacc[4][r], lane & 48);
        float il = 1.0f / lv;
        int qg = qt * 64 + w * 16 + quad * 4 + r;
        __hip_bfloat16* op = ctx + (((size_t)b * SEQ + qg) * NHEADS + h) * DHEAD + l16;
#pragma unroll
        for (int dt = 0; dt < 4; dt++)
            op[dt * 16] = __float2bfloat16(oacc[dt][r] * il);
    }
}

// ---------------------------------------------------------------------------
extern "C" void kernel_launch(void* const* d_in, const int* in_sizes, int n_in,
                              void* d_out, int out_size, void* d_ws, size_t ws_size,
                              hipStream_t stream)
{
    const float* x      = (const float*)d_in[0];   // [2,2048,1024]
    const float* qkv_w  = (const float*)d_in[1];   // [3072,1024]
    const float* qkv_b  = (const float*)d_in[2];   // [3072]
    const float* proj_w = (const float*)d_in[3];   // [1024,1024]
    const float* proj_b = (const float*)d_in[4];   // [1024]
    float* out = (float*)d_out;                    // [2,2048,1024]

    char* w = (char*)d_ws;
    __hip_bfloat16* qkb = (__hip_bfloat16*)w;  w += (size_t)MTOT * QKSTR * 2;         // 16 MB
    __hip_bfloat16* vtg = (__hip_bfloat16*)w;  w += (size_t)MTOT * DMODEL * 2;        //  8 MB
    __hip_bfloat16* ctx = (__hip_bfloat16*)w;  w += (size_t)MTOT * DMODEL * 2;        //  8 MB
    __hip_bfloat16* xb  = (__hip_bfloat16*)w;  w += (size_t)MTOT * DMODEL * 2;        //  8 MB
    __hip_bfloat16* wqk = (__hip_bfloat16*)w;  w += (size_t)3 * DMODEL * DMODEL * 2;  //  6 MB
    __hip_bfloat16* wpr = (__hip_bfloat16*)w;                                         //  2 MB

    const int na4 = MTOT * DMODEL / 4;
    const int nb4 = 3 * DMODEL * DMODEL / 4;
    const int nc4 = DMODEL * DMODEL / 4;

    // 0) fused bf16 casts
    cast_all_kernel<<<(na4 + nb4 + nc4 + 255) / 256, 256, 0, stream>>>(
        x, xb, na4, qkv_w, wqk, nb4, proj_w, wpr, nc4);

    // 1) qkv projection: q,k (RoPE'd) -> qkb; V -> vtg (transposed), fused
    //    128x128 tiles -> 32x24 = 768 blocks = 3/CU (m97 ladder sweet spot)
    gemm_bias_kernel<__hip_bfloat16, 1, 128, 128, 3>
        <<<dim3(MTOT / 128, (3 * DMODEL) / 128), 256, 0, stream>>>(
        xb, wqk, qkv_b, qkb, vtg, MTOT, 3 * DMODEL, DMODEL);

    // 2) causal MFMA flash attention -> ctx [B,S,H,Dh] bf16
    //    1024 blocks of 256 thr, 40KB LDS -> 4 blocks/CU
    flash_attn_mfma_kernel<<<dim3(BATCH * NHEADS, 32), 256, 0, stream>>>(qkb, vtg, ctx);

    // 3) out = ctx @ proj_w^T + proj_b -> fp32 d_out
    //    64x128 tiles -> 64x8 = 512 blocks = 2/CU
    gemm_bias_kernel<float, 0, 64, 128, 6>
        <<<dim3(MTOT / 64, DMODEL / 128), 256, 0, stream>>>(
        ctx, wpr, proj_b, out, nullptr, MTOT, DMODEL, DMODEL);
}